// Round 1
// baseline (353.191 us; speedup 1.0000x reference)
//
#include <hip/hip_runtime.h>
#include <hip/hip_bf16.h>
#include <math.h>

#define L_IN   1048576
#define NBATCH 16
#define T_FR   2049                 // frames per batch
#define NFR    (NBATCH*T_FR)        // 32784 total frames
#define NBINS  513
#define KLEN   1024
#define HOP    512
#define PADL   512

#define BM 64        // bins per block tile
#define BN 64        // frames per block tile
#define BK 64        // K step
#define PITCH 72     // LDS row pitch in shorts (64 + 8 pad -> 144B, 16B-aligned, ~2-way banks)

typedef __attribute__((ext_vector_type(8))) short short8;
typedef __attribute__((ext_vector_type(4))) float f32x4;

static __device__ __forceinline__ unsigned short f2bf(float f) {
  unsigned int u = __builtin_bit_cast(unsigned int, f);
  u += 0x7FFFu + ((u >> 16) & 1u);   // round-to-nearest-even
  return (unsigned short)(u >> 16);
}

static __device__ __forceinline__ unsigned long long pack4(float a, float b, float c, float d) {
  return (unsigned long long)f2bf(a)
       | ((unsigned long long)f2bf(b) << 16)
       | ((unsigned long long)f2bf(c) << 32)
       | ((unsigned long long)f2bf(d) << 48);
}

__global__ __launch_bounds__(256, 2)
void stft_mfma(const float* __restrict__ input,
               const float* __restrict__ basis,
               float* __restrict__ out)
{
  __shared__ unsigned short sX[BN][PITCH];  // [frame][k]
  __shared__ unsigned short sR[BM][PITCH];  // [bin][k] real basis
  __shared__ unsigned short sI[BM][PITCH];  // [bin][k] imag basis

  const int tid = threadIdx.x;
  const int frameBase = blockIdx.x * BN;
  const int binBase   = blockIdx.y * BM;

  // staging decomposition: 256 threads; thread covers rows r0+16i, cols kg*4..+3
  const int r0 = tid >> 4;   // 0..15
  const int kg = tid & 15;   // 0..15

  long xbase[4];
  int  xs0[4];
  const float* bR[4];
  const float* bI[4];
  #pragma unroll
  for (int i = 0; i < 4; ++i) {
    int r = r0 + i*16;
    int frame = frameBase + r;
    int fcl = frame < NFR ? frame : (NFR-1);
    unsigned int bb = (unsigned int)fcl / 2049u;
    int t = fcl - (int)(bb*2049u);
    xbase[i] = (long)bb * L_IN;
    xs0[i]   = t*HOP - PADL + kg*4;
    int bin = binBase + r;
    int rr = bin < 512 ? bin : 512;         // real rows 0..512
    int ri = bin + 513; ri = ri < 1025 ? ri : 1025;  // imag rows 513..1025
    bR[i] = basis + (long)rr*KLEN + kg*4;
    bI[i] = basis + (long)ri*KLEN + kg*4;
  }

  const int lane = tid & 63;
  const int wid  = tid >> 6;
  const int wrow = (wid >> 1) * 32;  // wave's bin offset within tile
  const int wcol = (wid & 1) * 32;   // wave's frame offset within tile
  const int lr   = lane & 15;
  const int koff = (lane >> 4) * 8;

  f32x4 zero = {0.f, 0.f, 0.f, 0.f};
  f32x4 accR[2][2], accI[2][2];
  #pragma unroll
  for (int m = 0; m < 2; ++m)
    #pragma unroll
    for (int n = 0; n < 2; ++n) { accR[m][n] = zero; accI[m][n] = zero; }

  for (int ks = 0; ks < KLEN/BK; ++ks) {
    const int k0 = ks*BK;
    // ---------------- stage (fp32 -> bf16) ----------------
    #pragma unroll
    for (int i = 0; i < 4; ++i) {
      const int r = r0 + i*16;
      int s0 = xs0[i] + k0;
      float4 xv;
      if (s0 >= 0 && s0 + 3 < L_IN) {
        xv = *(const float4*)&input[xbase[i] + s0];
      } else {
        float e[4];
        #pragma unroll
        for (int q = 0; q < 4; ++q) {
          int s = s0 + q;
          s = s < 0 ? -s : s;                       // left reflect
          s = s >= L_IN ? (2*L_IN - 2 - s) : s;     // right reflect
          e[q] = input[xbase[i] + s];
        }
        xv.x = e[0]; xv.y = e[1]; xv.z = e[2]; xv.w = e[3];
      }
      *(unsigned long long*)&sX[r][kg*4] = pack4(xv.x, xv.y, xv.z, xv.w);
      float4 rv = *(const float4*)(bR[i] + k0);
      *(unsigned long long*)&sR[r][kg*4] = pack4(rv.x, rv.y, rv.z, rv.w);
      float4 iv = *(const float4*)(bI[i] + k0);
      *(unsigned long long*)&sI[r][kg*4] = pack4(iv.x, iv.y, iv.z, iv.w);
    }
    __syncthreads();
    // ---------------- compute ----------------
    #pragma unroll
    for (int kk = 0; kk < 2; ++kk) {
      const int k = kk*32 + koff;
      short8 a0 = *(const short8*)&sR[wrow + lr][k];
      short8 a1 = *(const short8*)&sR[wrow + 16 + lr][k];
      short8 c0 = *(const short8*)&sI[wrow + lr][k];
      short8 c1 = *(const short8*)&sI[wrow + 16 + lr][k];
      short8 b0 = *(const short8*)&sX[wcol + lr][k];
      short8 b1 = *(const short8*)&sX[wcol + 16 + lr][k];
      accR[0][0] = __builtin_amdgcn_mfma_f32_16x16x32_bf16(a0, b0, accR[0][0], 0, 0, 0);
      accR[0][1] = __builtin_amdgcn_mfma_f32_16x16x32_bf16(a0, b1, accR[0][1], 0, 0, 0);
      accR[1][0] = __builtin_amdgcn_mfma_f32_16x16x32_bf16(a1, b0, accR[1][0], 0, 0, 0);
      accR[1][1] = __builtin_amdgcn_mfma_f32_16x16x32_bf16(a1, b1, accR[1][1], 0, 0, 0);
      accI[0][0] = __builtin_amdgcn_mfma_f32_16x16x32_bf16(c0, b0, accI[0][0], 0, 0, 0);
      accI[0][1] = __builtin_amdgcn_mfma_f32_16x16x32_bf16(c0, b1, accI[0][1], 0, 0, 0);
      accI[1][0] = __builtin_amdgcn_mfma_f32_16x16x32_bf16(c1, b0, accI[1][0], 0, 0, 0);
      accI[1][1] = __builtin_amdgcn_mfma_f32_16x16x32_bf16(c1, b1, accI[1][1], 0, 0, 0);
    }
    __syncthreads();
  }

  // ---------------- epilogue: magnitude + coalesced-ish store ----------------
  // C/D layout (m89-verified): col = lane&15 (frame), row = (lane>>4)*4 + reg (bin)
  #pragma unroll
  for (int n = 0; n < 2; ++n) {
    int frame = frameBase + wcol + n*16 + lr;
    if (frame >= NFR) continue;
    unsigned int bb = (unsigned int)frame / 2049u;
    int t = frame - (int)(bb*2049u);
    long obase = (long)bb * NBINS * T_FR + t;
    #pragma unroll
    for (int m = 0; m < 2; ++m) {
      int binB = binBase + wrow + m*16 + (lane >> 4)*4;
      #pragma unroll
      for (int j = 0; j < 4; ++j) {
        int bin = binB + j;
        if (bin < NBINS) {
          float re = accR[m][n][j];
          float im = accI[m][n][j];
          out[obase + (long)bin * T_FR] = sqrtf(re*re + im*im);
        }
      }
    }
  }
}

extern "C" void kernel_launch(void* const* d_in, const int* in_sizes, int n_in,
                              void* d_out, int out_size, void* d_ws, size_t ws_size,
                              hipStream_t stream) {
  const float* input = (const float*)d_in[0];
  const float* basis = (const float*)d_in[1];
  float* out = (float*)d_out;
  dim3 grid((NFR + BN - 1)/BN, (NBINS + BM - 1)/BM);  // (513, 9)
  stft_mfma<<<grid, dim3(256), 0, stream>>>(input, basis, out);
}

// Round 2
// 147.101 us; speedup vs baseline: 2.4010x; 2.4010x over previous
//
#include <hip/hip_runtime.h>
#include <hip/hip_bf16.h>
#include <math.h>

#define L_IN   1048576
#define NBATCH 16
#define T_FR   2049                 // frames per batch
#define NFR    (NBATCH*T_FR)        // 32784 total frames
#define NBINS  513
#define KLEN   1024
#define HOP    512
#define PADL   512

#define XWORDS 1049600              // padded samples per batch (L_IN + 1024)
#define BROWS  1152                 // interleaved basis rows, padded (576 pairs)

typedef __attribute__((ext_vector_type(8))) short short8;
typedef __attribute__((ext_vector_type(4))) float f32x4;

static __device__ __forceinline__ unsigned short f2bf(float f) {
  unsigned int u = __builtin_bit_cast(unsigned int, f);
  u += 0x7FFFu + ((u >> 16) & 1u);   // RNE
  return (unsigned short)(u >> 16);
}

static __device__ __forceinline__ unsigned long long pack4(float4 v) {
  return (unsigned long long)f2bf(v.x)
       | ((unsigned long long)f2bf(v.y) << 16)
       | ((unsigned long long)f2bf(v.z) << 32)
       | ((unsigned long long)f2bf(v.w) << 48);
}

#define GLOAD_LDS16(gsrc, ldst) \
  __builtin_amdgcn_global_load_lds((const __attribute__((address_space(1))) void*)(gsrc), \
                                   (__attribute__((address_space(3))) void*)(ldst), 16, 0, 0)

// ---------------- prep: basis fp32 -> bf16, interleaved [pair][{R,I}][1024] ----------------
__global__ void prep_basis(const float* __restrict__ basis, unsigned short* __restrict__ Bb) {
  const int row = blockIdx.x;          // 0..1151
  const int p = row >> 1, s = row & 1;
  unsigned long long v = 0ull;
  if (p < NBINS) {
    const int srcRow = s ? (p + NBINS) : p;   // imag rows live at 513..1025
    float4 x = *(const float4*)&basis[(long)srcRow * KLEN + threadIdx.x * 4];
    v = pack4(x);
  }
  *(unsigned long long*)(Bb + (long)row * KLEN + threadIdx.x * 4) = v;
}

// ---------------- prep: reflect-padded input fp32 -> bf16, X[16][1049600] ----------------
__global__ void prep_x(const float* __restrict__ input, unsigned short* __restrict__ Xb) {
  const int b  = blockIdx.y;
  const int j0 = blockIdx.x * 1024 + threadIdx.x * 4;   // 1025*1024 == 1049600 exactly
  const int s0 = j0 - PADL;
  float4 x;
  if (s0 >= 0 && s0 + 3 < L_IN) {
    x = *(const float4*)&input[(long)b * L_IN + s0];
  } else {
    float e[4];
    #pragma unroll
    for (int q = 0; q < 4; ++q) {
      int s = s0 + q;
      s = s < 0 ? -s : s;
      s = s >= L_IN ? (2 * L_IN - 2 - s) : s;
      e[q] = input[(long)b * L_IN + s];
    }
    x.x = e[0]; x.y = e[1]; x.z = e[2]; x.w = e[3];
  }
  *(unsigned long long*)(Xb + (long)b * XWORDS + j0) = pack4(x);
}

// ---------------- main: 128x128xK GEMM, global_load_lds staging, fused magnitude ----------------
__global__ __launch_bounds__(256, 2)
void stft_main(const unsigned short* __restrict__ Xb,
               const unsigned short* __restrict__ Bb,
               float* __restrict__ out)
{
  __shared__ unsigned short sA[128][64];   // basis rows (interleaved R/I)
  __shared__ unsigned short sB[128][64];   // frames

  const int tid  = threadIdx.x;
  const int lane = tid & 63;
  const int w    = tid >> 6;               // wave 0..3
  const int frameBase = blockIdx.x * 128;
  const int rowBase   = blockIdx.y * 128;  // interleaved basis row base

  // per-lane staging source pointers (wave w stages rows w*32 .. w*32+31, 4 groups of 8)
  const unsigned short* aP[4];
  const unsigned short* bP[4];
  const int lr8 = lane >> 3;               // row within 8-row group
  const int lc8 = lane & 7;                // 16B column
  #pragma unroll
  for (int q = 0; q < 4; ++q) {
    const int r = w * 32 + q * 8 + lr8;
    aP[q] = Bb + (long)(rowBase + r) * KLEN + lc8 * 8;
    int frame = frameBase + r;
    if (frame > NFR - 1) frame = NFR - 1;
    const int bb = frame / T_FR;
    const int t  = frame - bb * T_FR;
    bP[q] = Xb + (long)bb * XWORDS + t * HOP + lc8 * 8;
  }

  const int lr   = lane & 15;
  const int koff = (lane >> 4) * 8;
  const int wr   = (w >> 1) * 64;          // wave's row offset in tile
  const int wc   = (w & 1) * 64;           // wave's frame offset in tile

  f32x4 acc[4][4];
  #pragma unroll
  for (int m = 0; m < 4; ++m)
    #pragma unroll
    for (int n = 0; n < 4; ++n) acc[m][n] = (f32x4){0.f, 0.f, 0.f, 0.f};

  for (int ks = 0; ks < KLEN / 64; ++ks) {
    #pragma unroll
    for (int q = 0; q < 4; ++q) {
      GLOAD_LDS16(aP[q], &sA[w * 32 + q * 8][0]);  aP[q] += 64;
      GLOAD_LDS16(bP[q], &sB[w * 32 + q * 8][0]);  bP[q] += 64;
    }
    __syncthreads();
    #pragma unroll
    for (int kk = 0; kk < 2; ++kk) {
      const int k = kk * 32 + koff;
      short8 a[4], b[4];
      #pragma unroll
      for (int m = 0; m < 4; ++m) a[m] = *(const short8*)&sA[wr + m * 16 + lr][k];
      #pragma unroll
      for (int n = 0; n < 4; ++n) b[n] = *(const short8*)&sB[wc + n * 16 + lr][k];
      #pragma unroll
      for (int m = 0; m < 4; ++m)
        #pragma unroll
        for (int n = 0; n < 4; ++n)
          acc[m][n] = __builtin_amdgcn_mfma_f32_16x16x32_bf16(a[m], b[n], acc[m][n], 0, 0, 0);
    }
    __syncthreads();
  }

  // epilogue: C row = interleaved basis row; regs j = {R(p), I(p), R(p+1), I(p+1)}
  #pragma unroll
  for (int n = 0; n < 4; ++n) {
    const int frame = frameBase + wc + n * 16 + lr;
    if (frame >= NFR) continue;
    const int bb = frame / T_FR;
    const int t  = frame - bb * T_FR;
    const long ob = (long)bb * NBINS * T_FR + t;
    #pragma unroll
    for (int m = 0; m < 4; ++m) {
      const int grow = rowBase + wr + m * 16 + (lane >> 4) * 4;  // even
      const int p = grow >> 1;
      if (p < NBINS) {
        float re = acc[m][n][0], im = acc[m][n][1];
        out[ob + (long)p * T_FR] = sqrtf(re * re + im * im);
      }
      if (p + 1 < NBINS) {
        float re = acc[m][n][2], im = acc[m][n][3];
        out[ob + (long)(p + 1) * T_FR] = sqrtf(re * re + im * im);
      }
    }
  }
}

// ---------------- fallback (round-1 kernel) if ws is too small ----------------
#define FBM 64
#define FBN 64
#define FPITCH 72
__global__ __launch_bounds__(256, 2)
void stft_fallback(const float* __restrict__ input,
                   const float* __restrict__ basis,
                   float* __restrict__ out)
{
  __shared__ unsigned short sX[FBN][FPITCH];
  __shared__ unsigned short sR[FBM][FPITCH];
  __shared__ unsigned short sI[FBM][FPITCH];
  const int tid = threadIdx.x;
  const int frameBase = blockIdx.x * FBN;
  const int binBase   = blockIdx.y * FBM;
  const int r0 = tid >> 4;
  const int kg = tid & 15;
  long xbase[4]; int xs0[4];
  const float* bR[4]; const float* bI[4];
  #pragma unroll
  for (int i = 0; i < 4; ++i) {
    int r = r0 + i * 16;
    int frame = frameBase + r;
    int fcl = frame < NFR ? frame : (NFR - 1);
    unsigned int bb = (unsigned int)fcl / 2049u;
    int t = fcl - (int)(bb * 2049u);
    xbase[i] = (long)bb * L_IN;
    xs0[i]   = t * HOP - PADL + kg * 4;
    int bin = binBase + r;
    int rr = bin < 512 ? bin : 512;
    int ri = bin + 513; ri = ri < 1025 ? ri : 1025;
    bR[i] = basis + (long)rr * KLEN + kg * 4;
    bI[i] = basis + (long)ri * KLEN + kg * 4;
  }
  const int lane = tid & 63;
  const int wid  = tid >> 6;
  const int wrow = (wid >> 1) * 32;
  const int wcol = (wid & 1) * 32;
  const int lr   = lane & 15;
  const int koff = (lane >> 4) * 8;
  f32x4 zero = {0.f, 0.f, 0.f, 0.f};
  f32x4 accR[2][2], accI[2][2];
  #pragma unroll
  for (int m = 0; m < 2; ++m)
    #pragma unroll
    for (int n = 0; n < 2; ++n) { accR[m][n] = zero; accI[m][n] = zero; }
  for (int ks = 0; ks < KLEN / 64; ++ks) {
    const int k0 = ks * 64;
    #pragma unroll
    for (int i = 0; i < 4; ++i) {
      const int r = r0 + i * 16;
      int s0 = xs0[i] + k0;
      float4 xv;
      if (s0 >= 0 && s0 + 3 < L_IN) {
        xv = *(const float4*)&input[xbase[i] + s0];
      } else {
        float e[4];
        #pragma unroll
        for (int q = 0; q < 4; ++q) {
          int s = s0 + q;
          s = s < 0 ? -s : s;
          s = s >= L_IN ? (2 * L_IN - 2 - s) : s;
          e[q] = input[xbase[i] + s];
        }
        xv.x = e[0]; xv.y = e[1]; xv.z = e[2]; xv.w = e[3];
      }
      *(unsigned long long*)&sX[r][kg * 4] = pack4(xv);
      float4 rv = *(const float4*)(bR[i] + k0);
      *(unsigned long long*)&sR[r][kg * 4] = pack4(rv);
      float4 iv = *(const float4*)(bI[i] + k0);
      *(unsigned long long*)&sI[r][kg * 4] = pack4(iv);
    }
    __syncthreads();
    #pragma unroll
    for (int kk = 0; kk < 2; ++kk) {
      const int k = kk * 32 + koff;
      short8 a0 = *(const short8*)&sR[wrow + lr][k];
      short8 a1 = *(const short8*)&sR[wrow + 16 + lr][k];
      short8 c0 = *(const short8*)&sI[wrow + lr][k];
      short8 c1 = *(const short8*)&sI[wrow + 16 + lr][k];
      short8 b0 = *(const short8*)&sX[wcol + lr][k];
      short8 b1 = *(const short8*)&sX[wcol + 16 + lr][k];
      accR[0][0] = __builtin_amdgcn_mfma_f32_16x16x32_bf16(a0, b0, accR[0][0], 0, 0, 0);
      accR[0][1] = __builtin_amdgcn_mfma_f32_16x16x32_bf16(a0, b1, accR[0][1], 0, 0, 0);
      accR[1][0] = __builtin_amdgcn_mfma_f32_16x16x32_bf16(a1, b0, accR[1][0], 0, 0, 0);
      accR[1][1] = __builtin_amdgcn_mfma_f32_16x16x32_bf16(a1, b1, accR[1][1], 0, 0, 0);
      accI[0][0] = __builtin_amdgcn_mfma_f32_16x16x32_bf16(c0, b0, accI[0][0], 0, 0, 0);
      accI[0][1] = __builtin_amdgcn_mfma_f32_16x16x32_bf16(c0, b1, accI[0][1], 0, 0, 0);
      accI[1][0] = __builtin_amdgcn_mfma_f32_16x16x32_bf16(c1, b0, accI[1][0], 0, 0, 0);
      accI[1][1] = __builtin_amdgcn_mfma_f32_16x16x32_bf16(c1, b1, accI[1][1], 0, 0, 0);
    }
    __syncthreads();
  }
  #pragma unroll
  for (int n = 0; n < 2; ++n) {
    int frame = frameBase + wcol + n * 16 + lr;
    if (frame >= NFR) continue;
    unsigned int bb = (unsigned int)frame / 2049u;
    int t = frame - (int)(bb * 2049u);
    long obase = (long)bb * NBINS * T_FR + t;
    #pragma unroll
    for (int m = 0; m < 2; ++m) {
      int binB = binBase + wrow + m * 16 + (lane >> 4) * 4;
      #pragma unroll
      for (int j = 0; j < 4; ++j) {
        int bin = binB + j;
        if (bin < NBINS) {
          float re = accR[m][n][j];
          float im = accI[m][n][j];
          out[obase + (long)bin * T_FR] = sqrtf(re * re + im * im);
        }
      }
    }
  }
}

extern "C" void kernel_launch(void* const* d_in, const int* in_sizes, int n_in,
                              void* d_out, int out_size, void* d_ws, size_t ws_size,
                              hipStream_t stream) {
  const float* input = (const float*)d_in[0];
  const float* basis = (const float*)d_in[1];
  float* out = (float*)d_out;

  const size_t xBytes = (size_t)NBATCH * XWORDS * 2;
  const size_t bBytes = (size_t)BROWS * KLEN * 2;
  if (ws_size >= xBytes + bBytes) {
    unsigned short* Xb = (unsigned short*)d_ws;
    unsigned short* Bb = Xb + (size_t)NBATCH * XWORDS;
    prep_x<<<dim3(1025, 16), 256, 0, stream>>>(input, Xb);
    prep_basis<<<dim3(BROWS), 256, 0, stream>>>(basis, Bb);
    stft_main<<<dim3((NFR + 127) / 128, BROWS / 128), 256, 0, stream>>>(Xb, Bb, out);
  } else {
    dim3 grid((NFR + FBN - 1) / FBN, (NBINS + FBM - 1) / FBM);
    stft_fallback<<<grid, dim3(256), 0, stream>>>(input, basis, out);
  }
}

// Round 3
// 116.858 us; speedup vs baseline: 3.0224x; 1.2588x over previous
//
#include <hip/hip_runtime.h>
#include <hip/hip_bf16.h>
#include <math.h>

#define L_IN   1048576
#define NBATCH 16
#define T_FR   2049                 // frames per batch
#define NFR    (NBATCH*T_FR)        // 32784 total frames
#define NBINS  513
#define KLEN   1024
#define HOP    512
#define PADL   512

#define XWORDS 1049600              // padded samples per batch (L_IN + 1024)
#define BROWS  1152                 // interleaved basis rows, padded (576 pairs)

#define NTX 257                     // frame tiles (128 each)
#define NTY 9                       // basis-row tiles (128 each)
#define NWG (NTX*NTY)               // 2313

typedef __attribute__((ext_vector_type(8))) short short8;
typedef __attribute__((ext_vector_type(4))) float f32x4;

static __device__ __forceinline__ unsigned short f2bf(float f) {
  unsigned int u = __builtin_bit_cast(unsigned int, f);
  u += 0x7FFFu + ((u >> 16) & 1u);   // RNE
  return (unsigned short)(u >> 16);
}

static __device__ __forceinline__ unsigned long long pack4(float4 v) {
  return (unsigned long long)f2bf(v.x)
       | ((unsigned long long)f2bf(v.y) << 16)
       | ((unsigned long long)f2bf(v.z) << 32)
       | ((unsigned long long)f2bf(v.w) << 48);
}

#define GLOAD_LDS16(gsrc, ldst) \
  __builtin_amdgcn_global_load_lds((const __attribute__((address_space(1))) void*)(gsrc), \
                                   (__attribute__((address_space(3))) void*)(ldst), 16, 0, 0)

// ---------------- prep: basis fp32 -> bf16, interleaved [pair][{R,I}][1024] ----------------
__global__ void prep_basis(const float* __restrict__ basis, unsigned short* __restrict__ Bb) {
  const int row = blockIdx.x;          // 0..1151
  const int p = row >> 1, s = row & 1;
  unsigned long long v = 0ull;
  if (p < NBINS) {
    const int srcRow = s ? (p + NBINS) : p;   // imag rows live at 513..1025
    float4 x = *(const float4*)&basis[(long)srcRow * KLEN + threadIdx.x * 4];
    v = pack4(x);
  }
  *(unsigned long long*)(Bb + (long)row * KLEN + threadIdx.x * 4) = v;
}

// ---------------- prep: reflect-padded input fp32 -> bf16, X[16][1049600] ----------------
__global__ void prep_x(const float* __restrict__ input, unsigned short* __restrict__ Xb) {
  const int b  = blockIdx.y;
  const int j0 = blockIdx.x * 1024 + threadIdx.x * 4;   // 1025*1024 == 1049600 exactly
  const int s0 = j0 - PADL;
  float4 x;
  if (s0 >= 0 && s0 + 3 < L_IN) {
    x = *(const float4*)&input[(long)b * L_IN + s0];
  } else {
    float e[4];
    #pragma unroll
    for (int q = 0; q < 4; ++q) {
      int s = s0 + q;
      s = s < 0 ? -s : s;
      s = s >= L_IN ? (2 * L_IN - 2 - s) : s;
      e[q] = input[(long)b * L_IN + s];
    }
    x.x = e[0]; x.y = e[1]; x.z = e[2]; x.w = e[3];
  }
  *(unsigned long long*)(Xb + (long)b * XWORDS + j0) = pack4(x);
}

// ---------------- main: 128x128 tile, 2-deep counted-vmcnt pipeline, XOR-swizzled LDS ----------------
// LDS chunk swizzle: physical 16B-chunk = logical chunk ^ (row & 7).
// gload_lds dest stays LINEAR; the global SOURCE address is inverse-swizzled per lane (rule 21).
__global__ __launch_bounds__(256, 2)
void stft_main(const unsigned short* __restrict__ Xb,
               const unsigned short* __restrict__ Bb,
               float* __restrict__ out)
{
  __shared__ unsigned short sA2[2][128][64];   // basis rows (interleaved R/I), 32 KB
  __shared__ unsigned short sB2[2][128][64];   // frames, 32 KB

  const int tid  = threadIdx.x;
  const int lane = tid & 63;
  const int w    = tid >> 6;               // wave 0..3

  // ---- bijective XCD swizzle (m204), y-fast so one XCD chunk reuses an Xb slab ----
  const int bid = blockIdx.x;
  const int qq = NWG >> 3, rr = NWG & 7;   // 289, 1
  const int xcd = bid & 7, idx = bid >> 3;
  const int wg = (xcd < rr) ? (xcd * (qq + 1) + idx) : (rr * (qq + 1) + (xcd - rr) * qq + idx);
  const int frameBase = (wg / NTY) * 128;
  const int rowBase   = (wg % NTY) * 128;

  // ---- staging source pointers: wave w stages rows w*32..+31 (4 groups of 8) ----
  const unsigned short* aP[4];
  const unsigned short* bP[4];
  const int lr8 = lane >> 3;               // row within 8-row group (== row&7)
  const int lc8 = lane & 7;                // physical 16B chunk
  const int cs  = (lc8 ^ lr8) * 8;         // inverse-swizzled source chunk offset (shorts)
  #pragma unroll
  for (int q = 0; q < 4; ++q) {
    const int r = w * 32 + q * 8 + lr8;
    aP[q] = Bb + (long)(rowBase + r) * KLEN + cs;
    int frame = frameBase + r;
    if (frame > NFR - 1) frame = NFR - 1;
    const int bb = frame / T_FR;
    const int t  = frame - bb * T_FR;
    bP[q] = Xb + (long)bb * XWORDS + t * HOP + cs;
  }

  const int lr   = lane & 15;
  const int ql   = lane >> 4;              // quarter-wave -> base chunk
  const int e    = lane & 7;               // row&7 for fragment rows
  const int wr   = (w >> 1) * 64;          // wave's row offset in tile
  const int wc   = (w & 1) * 64;           // wave's frame offset in tile

  f32x4 acc[4][4];
  #pragma unroll
  for (int m = 0; m < 4; ++m)
    #pragma unroll
    for (int n = 0; n < 4; ++n) acc[m][n] = (f32x4){0.f, 0.f, 0.f, 0.f};

  // stage K-tile ks into buffer b (8 gload_lds instructions per wave)
  #define STAGE(ks, b) do {                                            \
    _Pragma("unroll")                                                   \
    for (int q = 0; q < 4; ++q) {                                       \
      GLOAD_LDS16(aP[q] + (ks) * 64, &sA2[b][w * 32 + q * 8][0]);       \
      GLOAD_LDS16(bP[q] + (ks) * 64, &sB2[b][w * 32 + q * 8][0]);       \
    }                                                                   \
  } while (0)

  // compute one K-tile from buffer b (swizzled ds_reads + 32 MFMA)
  #define COMPUTE(b) do {                                               \
    _Pragma("unroll")                                                   \
    for (int kk = 0; kk < 2; ++kk) {                                    \
      const int c = ((kk * 4 + ql) ^ e) * 8;                            \
      short8 a[4], bfr[4];                                              \
      _Pragma("unroll")                                                 \
      for (int m = 0; m < 4; ++m) a[m]   = *(const short8*)&sA2[b][wr + m * 16 + lr][c]; \
      _Pragma("unroll")                                                 \
      for (int n = 0; n < 4; ++n) bfr[n] = *(const short8*)&sB2[b][wc + n * 16 + lr][c]; \
      _Pragma("unroll")                                                 \
      for (int m = 0; m < 4; ++m)                                       \
        _Pragma("unroll")                                               \
        for (int n = 0; n < 4; ++n)                                     \
          acc[m][n] = __builtin_amdgcn_mfma_f32_16x16x32_bf16(a[m], bfr[n], acc[m][n], 0, 0, 0); \
    }                                                                   \
  } while (0)

  // ---- prologue: 2 K-tiles in flight ----
  STAGE(0, 0);
  STAGE(1, 1);

  // ---- main loop: 15 iters with counted vmcnt (never drain to 0) ----
  for (int ks = 0; ks < 15; ++ks) {
    asm volatile("s_waitcnt vmcnt(8)" ::: "memory");  // stage(ks) landed; stage(ks+1) may fly
    __builtin_amdgcn_s_barrier();
    __builtin_amdgcn_sched_barrier(0);
    COMPUTE(ks & 1);
    __builtin_amdgcn_sched_barrier(0);
    __builtin_amdgcn_s_barrier();                      // all waves done reading buf[ks&1]
    __builtin_amdgcn_sched_barrier(0);
    if (ks < 14) STAGE(ks + 2, ks & 1);                // refill just-freed buffer
  }
  // ---- peeled last K-tile ----
  asm volatile("s_waitcnt vmcnt(0)" ::: "memory");
  __builtin_amdgcn_s_barrier();
  __builtin_amdgcn_sched_barrier(0);
  COMPUTE(1);

  #undef STAGE
  #undef COMPUTE

  // ---- epilogue: magnitude; regs j = {R(p), I(p), R(p+1), I(p+1)} ----
  #pragma unroll
  for (int n = 0; n < 4; ++n) {
    const int frame = frameBase + wc + n * 16 + lr;
    if (frame >= NFR) continue;
    const int bb = frame / T_FR;
    const int t  = frame - bb * T_FR;
    const long ob = (long)bb * NBINS * T_FR + t;
    #pragma unroll
    for (int m = 0; m < 4; ++m) {
      const int grow = rowBase + wr + m * 16 + (lane >> 4) * 4;  // even
      const int p = grow >> 1;
      if (p < NBINS) {
        float re = acc[m][n][0], im = acc[m][n][1];
        out[ob + (long)p * T_FR] = sqrtf(re * re + im * im);
      }
      if (p + 1 < NBINS) {
        float re = acc[m][n][2], im = acc[m][n][3];
        out[ob + (long)(p + 1) * T_FR] = sqrtf(re * re + im * im);
      }
    }
  }
}

// ---------------- fallback (round-1 kernel) if ws is too small ----------------
#define FBM 64
#define FBN 64
#define FPITCH 72
__global__ __launch_bounds__(256, 2)
void stft_fallback(const float* __restrict__ input,
                   const float* __restrict__ basis,
                   float* __restrict__ out)
{
  __shared__ unsigned short sX[FBN][FPITCH];
  __shared__ unsigned short sR[FBM][FPITCH];
  __shared__ unsigned short sI[FBM][FPITCH];
  const int tid = threadIdx.x;
  const int frameBase = blockIdx.x * FBN;
  const int binBase   = blockIdx.y * FBM;
  const int r0 = tid >> 4;
  const int kg = tid & 15;
  long xbase[4]; int xs0[4];
  const float* bR[4]; const float* bI[4];
  #pragma unroll
  for (int i = 0; i < 4; ++i) {
    int r = r0 + i * 16;
    int frame = frameBase + r;
    int fcl = frame < NFR ? frame : (NFR - 1);
    unsigned int bb = (unsigned int)fcl / 2049u;
    int t = fcl - (int)(bb * 2049u);
    xbase[i] = (long)bb * L_IN;
    xs0[i]   = t * HOP - PADL + kg * 4;
    int bin = binBase + r;
    int rr = bin < 512 ? bin : 512;
    int ri = bin + 513; ri = ri < 1025 ? ri : 1025;
    bR[i] = basis + (long)rr * KLEN + kg * 4;
    bI[i] = basis + (long)ri * KLEN + kg * 4;
  }
  const int lane = tid & 63;
  const int wid  = tid >> 6;
  const int wrow = (wid >> 1) * 32;
  const int wcol = (wid & 1) * 32;
  const int lr   = lane & 15;
  const int koff = (lane >> 4) * 8;
  f32x4 zero = {0.f, 0.f, 0.f, 0.f};
  f32x4 accR[2][2], accI[2][2];
  #pragma unroll
  for (int m = 0; m < 2; ++m)
    #pragma unroll
    for (int n = 0; n < 2; ++n) { accR[m][n] = zero; accI[m][n] = zero; }
  for (int ks = 0; ks < KLEN / 64; ++ks) {
    const int k0 = ks * 64;
    #pragma unroll
    for (int i = 0; i < 4; ++i) {
      const int r = r0 + i * 16;
      int s0 = xs0[i] + k0;
      float4 xv;
      if (s0 >= 0 && s0 + 3 < L_IN) {
        xv = *(const float4*)&input[xbase[i] + s0];
      } else {
        float ee[4];
        #pragma unroll
        for (int q = 0; q < 4; ++q) {
          int s = s0 + q;
          s = s < 0 ? -s : s;
          s = s >= L_IN ? (2 * L_IN - 2 - s) : s;
          ee[q] = input[xbase[i] + s];
        }
        xv.x = ee[0]; xv.y = ee[1]; xv.z = ee[2]; xv.w = ee[3];
      }
      *(unsigned long long*)&sX[r][kg * 4] = pack4(xv);
      float4 rv = *(const float4*)(bR[i] + k0);
      *(unsigned long long*)&sR[r][kg * 4] = pack4(rv);
      float4 iv = *(const float4*)(bI[i] + k0);
      *(unsigned long long*)&sI[r][kg * 4] = pack4(iv);
    }
    __syncthreads();
    #pragma unroll
    for (int kk = 0; kk < 2; ++kk) {
      const int k = kk * 32 + koff;
      short8 a0 = *(const short8*)&sR[wrow + lr][k];
      short8 a1 = *(const short8*)&sR[wrow + 16 + lr][k];
      short8 c0 = *(const short8*)&sI[wrow + lr][k];
      short8 c1 = *(const short8*)&sI[wrow + 16 + lr][k];
      short8 b0 = *(const short8*)&sX[wcol + lr][k];
      short8 b1 = *(const short8*)&sX[wcol + 16 + lr][k];
      accR[0][0] = __builtin_amdgcn_mfma_f32_16x16x32_bf16(a0, b0, accR[0][0], 0, 0, 0);
      accR[0][1] = __builtin_amdgcn_mfma_f32_16x16x32_bf16(a0, b1, accR[0][1], 0, 0, 0);
      accR[1][0] = __builtin_amdgcn_mfma_f32_16x16x32_bf16(a1, b0, accR[1][0], 0, 0, 0);
      accR[1][1] = __builtin_amdgcn_mfma_f32_16x16x32_bf16(a1, b1, accR[1][1], 0, 0, 0);
      accI[0][0] = __builtin_amdgcn_mfma_f32_16x16x32_bf16(c0, b0, accI[0][0], 0, 0, 0);
      accI[0][1] = __builtin_amdgcn_mfma_f32_16x16x32_bf16(c0, b1, accI[0][1], 0, 0, 0);
      accI[1][0] = __builtin_amdgcn_mfma_f32_16x16x32_bf16(c1, b0, accI[1][0], 0, 0, 0);
      accI[1][1] = __builtin_amdgcn_mfma_f32_16x16x32_bf16(c1, b1, accI[1][1], 0, 0, 0);
    }
    __syncthreads();
  }
  #pragma unroll
  for (int n = 0; n < 2; ++n) {
    int frame = frameBase + wcol + n * 16 + lr;
    if (frame >= NFR) continue;
    unsigned int bb = (unsigned int)frame / 2049u;
    int t = frame - (int)(bb * 2049u);
    long obase = (long)bb * NBINS * T_FR + t;
    #pragma unroll
    for (int m = 0; m < 2; ++m) {
      int binB = binBase + wrow + m * 16 + (lane >> 4) * 4;
      #pragma unroll
      for (int j = 0; j < 4; ++j) {
        int bin = binB + j;
        if (bin < NBINS) {
          float re = accR[m][n][j];
          float im = accI[m][n][j];
          out[obase + (long)bin * T_FR] = sqrtf(re * re + im * im);
        }
      }
    }
  }
}

extern "C" void kernel_launch(void* const* d_in, const int* in_sizes, int n_in,
                              void* d_out, int out_size, void* d_ws, size_t ws_size,
                              hipStream_t stream) {
  const float* input = (const float*)d_in[0];
  const float* basis = (const float*)d_in[1];
  float* out = (float*)d_out;

  const size_t xBytes = (size_t)NBATCH * XWORDS * 2;
  const size_t bBytes = (size_t)BROWS * KLEN * 2;
  if (ws_size >= xBytes + bBytes) {
    unsigned short* Xb = (unsigned short*)d_ws;
    unsigned short* Bb = Xb + (size_t)NBATCH * XWORDS;
    prep_x<<<dim3(1025, 16), 256, 0, stream>>>(input, Xb);
    prep_basis<<<dim3(BROWS), 256, 0, stream>>>(basis, Bb);
    stft_main<<<dim3(NWG), 256, 0, stream>>>(Xb, Bb, out);
  } else {
    dim3 grid((NFR + FBN - 1) / FBN, (NBINS + FBM - 1) / FBM);
    stft_fallback<<<grid, dim3(256), 0, stream>>>(input, basis, out);
  }
}